// Round 11
// baseline (123.327 us; speedup 1.0000x reference)
//
#include <hip/hip_runtime.h>

#define NB 4
#define NS 2048
#define ND 1024
#define NH 16
#define NDH 64
#define NR 12
#define NRH 192

typedef __attribute__((ext_vector_type(8))) short bf16x8;
typedef __attribute__((ext_vector_type(4))) float f32x4;

__device__ __forceinline__ unsigned short rnbf(float f) {
  unsigned u = __float_as_uint(f);
  u += 0x7fffu + ((u >> 16) & 1u);
  return (unsigned short)(u >> 16);
}
__device__ __forceinline__ float bf2f(unsigned short h) {
  return __uint_as_float(((unsigned)h) << 16);
}

// v_cvt_pk_bf16_f32: dst[15:0]=bf16(a) RNE, dst[31:16]=bf16(b)
__device__ __forceinline__ unsigned cvtpk(float a, float b) {
  unsigned r;
  asm("v_cvt_pk_bf16_f32 %0, %1, %2" : "=v"(r) : "v"(a), "v"(b));
  return r;
}
__device__ __forceinline__ uint4 pk_hi(float4 u, float4 w) {
  uint4 h;
  h.x = cvtpk(u.x, u.y); h.y = cvtpk(u.z, u.w);
  h.z = cvtpk(w.x, w.y); h.w = cvtpk(w.z, w.w);
  return h;
}
__device__ __forceinline__ unsigned lo2(float a, float b, unsigned hh) {
  float ah = __uint_as_float(hh << 16);
  float bh = __uint_as_float(hh & 0xffff0000u);
  return cvtpk(a - ah, b - bh);
}
__device__ __forceinline__ uint4 pk_lo(float4 u, float4 w, uint4 h) {
  uint4 l;
  l.x = lo2(u.x, u.y, h.x); l.y = lo2(u.z, u.w, h.y);
  l.z = lo2(w.x, w.y, h.z); l.w = lo2(w.z, w.w, h.w);
  return l;
}

__device__ __forceinline__ void gload16(const void* g, void* l) {
  __builtin_amdgcn_global_load_lds(
      (const __attribute__((address_space(1))) unsigned int*)g,
      (__attribute__((address_space(3))) unsigned int*)l, 16, 0, 0);
}

#define MFMA(a, b, c) __builtin_amdgcn_mfma_f32_16x16x32_bf16(a, b, c, 0, 0, 0)

// ---------------------------------------------------------------------------
// Wq_eff[b,h,r,e] = sum_d U[b,h,r,d] * W_Q[h*64+d, e]  -> hi/lo bf16
// ---------------------------------------------------------------------------
__global__ __launch_bounds__(256) void build_wqeff(const float* __restrict__ U,
                                                   const float* __restrict__ WQ,
                                                   unsigned short* __restrict__ wqhi,
                                                   unsigned short* __restrict__ wqlo) {
  int idx = blockIdx.x;
  int hr = idx % (NH * NR);
  int h = hr / NR;
  __shared__ float u[NDH];
  int t = threadIdx.x;
  if (t < NDH) u[t] = U[(size_t)idx * NDH + t];
  __syncthreads();
  int e0 = t * 4;
  float a0 = 0.f, a1 = 0.f, a2 = 0.f, a3 = 0.f;
  const float* wbase = WQ + (size_t)h * NDH * ND + e0;
#pragma unroll 4
  for (int d = 0; d < NDH; ++d) {
    float uv = u[d];
    const float* wr = wbase + (size_t)d * ND;
    a0 += uv * wr[0]; a1 += uv * wr[1]; a2 += uv * wr[2]; a3 += uv * wr[3];
  }
  ushort4 h4, l4;
  h4.x = rnbf(a0); l4.x = rnbf(a0 - bf2f(h4.x));
  h4.y = rnbf(a1); l4.y = rnbf(a1 - bf2f(h4.y));
  h4.z = rnbf(a2); l4.z = rnbf(a2 - bf2f(h4.z));
  h4.w = rnbf(a3); l4.w = rnbf(a3 - bf2f(h4.w));
  *(ushort4*)&wqhi[(size_t)idx * ND + e0] = h4;
  *(ushort4*)&wqlo[(size_t)idx * ND + e0] = l4;
}

// ---------------------------------------------------------------------------
// gemm_tn: C^T-oriented GEMM, BM=64, BN=64, BK=128 (8 fat K-steps).
//   out[n][m] = sum_k A[m][k]*B[n][k]; M=2048(s), N=192(rh), K=1024.
// A = fp32 reg-staged to bf16 (pair iff PAIR), swizzled LDS (256B rows).
// B = bf16 (pair iff PAIR) via global_load_lds, pre-swizzled source.
// 4 waves (2m x 2n), wave-tile 32x32, 48 MFMA/wave/step (PAIR).
// Grid 384 (1D), XCD-decoded: 3 n-blocks of one (b,m0) adjacent per XCD;
// per-XCD working set ~4MB = L2.
// ---------------------------------------------------------------------------
template <bool PAIR>
__global__ __launch_bounds__(256) void gemm_tn(
    const float* __restrict__ Af,
    const unsigned short* __restrict__ Bhi, const unsigned short* __restrict__ Blo,
    unsigned short* __restrict__ C0, unsigned short* __restrict__ C1) {
  constexpr int NBUF = PAIR ? 2 : 1;
  constexpr int PLANE = 64 * 128 * 2;  // bytes per LDS plane (16KB)
  __shared__ unsigned short As[NBUF][64 * 128];
  __shared__ unsigned short Bs[NBUF][64 * 128];
  const int tid = threadIdx.x;
  const int lane = tid & 63;
  const int wid = tid >> 6;
  const int wm = wid >> 1, wn = wid & 1;

  // XCD decode: lin 0..383; bijective; 3 n-blocks of (b,m0) adjacent.
  int lin = blockIdx.x;
  int xcd = lin & 7, slot = lin >> 3;  // slot 0..47
  int b = slot / 12;
  int rem = slot % 12;                 // 4 m-chunks x 3 n
  int m0 = ((rem / 3) * 8 + xcd) * 64; // 0..1984
  int n0 = (rem % 3) * 64;

  const float* pA = Af + (size_t)b * NS * ND;
  const unsigned short* pBhi = Bhi + (size_t)b * NRH * ND;
  const unsigned short* pBlo = PAIR ? Blo + (size_t)b * NRH * ND : nullptr;

  const int arow = tid >> 2;        // 0..63
  const int aq = (tid & 3) * 4;     // A slot base {0,4,8,12}

  f32x4 acc[2][2];
#pragma unroll
  for (int i = 0; i < 2; ++i)
#pragma unroll
    for (int j = 0; j < 2; ++j) acc[i][j] = (f32x4){0.f, 0.f, 0.f, 0.f};

  for (int k0 = 0; k0 < ND; k0 += 128) {
    // ---- B: bf16 via global_load_lds (pre-swizzled source), 4 rows/inst
#pragma unroll
    for (int cc = 0; cc < 4; ++cc) {
      int c = wid * 4 + cc;               // chunk 0..15 (4 rows each)
      int lrow = c * 4 + (lane >> 4);     // local B row 0..63
      int sslot = (lane & 15) ^ (lrow & 7);
      size_t gaddr = (size_t)(n0 + lrow) * ND + k0 + sslot * 8;
      gload16(&pBhi[gaddr], (char*)&Bs[0][0] + c * 1024);
      if (PAIR) gload16(&pBlo[gaddr], (char*)&Bs[NBUF - 1][0] + c * 1024);
    }
    // ---- A: fp32 -> bf16 (pair) reg-stage, swizzled ds_write (4x16B/thread)
    {
      const float* asrc = pA + (size_t)(m0 + arow) * ND + k0 + aq * 8;
      char* abase = (char*)&As[0][0] + arow * 256;
#pragma unroll
      for (int jj = 0; jj < 4; ++jj) {
        float4 u = *(const float4*)(asrc + jj * 8);
        float4 v = *(const float4*)(asrc + jj * 8 + 4);
        uint4 h = pk_hi(u, v);
        char* dst = abase + (((aq + jj) ^ (arow & 7)) << 4);
        *(uint4*)dst = h;
        if (PAIR) *(uint4*)(dst + PLANE) = pk_lo(u, v, h);
      }
    }
    __syncthreads();

#pragma unroll
    for (int kk = 0; kk < 128; kk += 32) {
      int sig = (kk >> 3) + (lane >> 4);  // 0..15
      bf16x8 ah[2], al[2], bh[2], bl[2];
#pragma unroll
      for (int fm = 0; fm < 2; ++fm) {
        int r = wm * 32 + fm * 16 + (lane & 15);
        int off = r * 256 + ((sig ^ (r & 7)) << 4);
        ah[fm] = *(const bf16x8*)((const char*)&As[0][0] + off);
        if (PAIR) al[fm] = *(const bf16x8*)((const char*)&As[0][0] + PLANE + off);
      }
#pragma unroll
      for (int fn = 0; fn < 2; ++fn) {
        int r = wn * 32 + fn * 16 + (lane & 15);
        int off = r * 256 + ((sig ^ (r & 7)) << 4);
        bh[fn] = *(const bf16x8*)((const char*)&Bs[0][0] + off);
        if (PAIR) bl[fn] = *(const bf16x8*)((const char*)&Bs[0][0] + PLANE + off);
      }
#pragma unroll
      for (int fm = 0; fm < 2; ++fm)
#pragma unroll
        for (int fn = 0; fn < 2; ++fn) {
          acc[fm][fn] = MFMA(ah[fm], bh[fn], acc[fm][fn]);
          if (PAIR) {
            acc[fm][fn] = MFMA(ah[fm], bl[fn], acc[fm][fn]);
            acc[fm][fn] = MFMA(al[fm], bh[fn], acc[fm][fn]);
          }
        }
    }
    __syncthreads();
  }

  // ---- transposed epilogue: lane's 4 acc values are 4 consecutive m=s
  const int jr = lane >> 4, cl = lane & 15;
#pragma unroll
  for (int fm = 0; fm < 2; ++fm)
#pragma unroll
    for (int fn = 0; fn < 2; ++fn) {
      f32x4 v = acc[fm][fn];
      int s = m0 + wm * 32 + fm * 16 + jr * 4;
      int rh = n0 + wn * 32 + fn * 16 + cl;
      int orow = PAIR ? rh : (rh % NR) * NH + rh / NR;
      size_t o = ((size_t)b * NRH + orow) * NS + s;
      ushort4 h4;
      h4.x = rnbf(v[0]); h4.y = rnbf(v[1]);
      h4.z = rnbf(v[2]); h4.w = rnbf(v[3]);
      *(ushort4*)&C0[o] = h4;
      if (PAIR) {
        ushort4 l4;
        l4.x = rnbf(v[0] - bf2f(h4.x)); l4.y = rnbf(v[1] - bf2f(h4.y));
        l4.z = rnbf(v[2] - bf2f(h4.z)); l4.w = rnbf(v[3] - bf2f(h4.w));
        *(ushort4*)&C1[o] = l4;
      }
    }
}

// ---------------------------------------------------------------------------
// G2: T1 partials. P[z][m][e] = sum_{s in chunk z} s1[m][s]*K[s][e]
// (round-9 version: hi/lo pair; in-kernel K transpose+convert; K-reg
// prefetch across MFMA; XCD decode.)
// ---------------------------------------------------------------------------
__global__ __launch_bounds__(256) void gemm_g2(
    const unsigned short* __restrict__ Ahi, const unsigned short* __restrict__ Alo,
    const float* __restrict__ Kf, float* __restrict__ P,
    int kchunk, int nz) {
  __shared__ unsigned short As[2][64 * 64];
  __shared__ unsigned short Bs[2][64 * 64];
  __shared__ float tbuf[64 * 68];
  const int tid = threadIdx.x;
  const int lane = tid & 63;
  const int wid = tid >> 6;
  const int wm = wid >> 1, wn = wid & 1;

  int lin = blockIdx.x;
  int bz, m_idx, n_idx;
  if (nz == 16) {
    int xcd = lin & 7, slot = lin >> 3;
    bz = xcd + 8 * (slot / 48);
    int rem = slot % 48;
    m_idx = rem / 16; n_idx = rem % 16;
  } else {
    bz = lin / 48;
    int rem = lin % 48;
    m_idx = rem / 16; n_idx = rem % 16;
  }
  const int m0 = m_idx * 64, n0 = n_idx * 64;
  const int b = bz % NB;
  const int kbeg = (bz / NB) * kchunk;
  const unsigned short* pAhi = Ahi + (size_t)b * NRH * NS;
  const unsigned short* pAlo = Alo + (size_t)b * NRH * NS;
  const float* pK = Kf + (size_t)b * NS * ND;

  const int rsub = lane >> 3;
  const int slotg = (lane & 7) ^ rsub;
  const int sr = tid >> 2;
  const int eg = (tid & 3) * 16;

  f32x4 acc[2][2];
#pragma unroll
  for (int i = 0; i < 2; ++i)
#pragma unroll
    for (int j = 0; j < 2; ++j) acc[i][j] = (f32x4){0.f, 0.f, 0.f, 0.f};

  float4 kr0, kr1, kr2, kr3;
  {
    const float* ksrc = pK + (size_t)(kbeg + sr) * ND + n0 + eg;
    kr0 = *(const float4*)(ksrc + 0);
    kr1 = *(const float4*)(ksrc + 4);
    kr2 = *(const float4*)(ksrc + 8);
    kr3 = *(const float4*)(ksrc + 12);
  }

  for (int k0 = kbeg; k0 < kbeg + kchunk; k0 += 64) {
#pragma unroll
    for (int cc = 0; cc < 2; ++cc) {
      int c = wid * 2 + cc;
      int grow = m0 + c * 8 + rsub;
      gload16(&pAhi[(size_t)grow * NS + k0 + slotg * 8], &As[0][c * 512]);
      gload16(&pAlo[(size_t)grow * NS + k0 + slotg * 8], &As[1][c * 512]);
    }
    {
      float* td = &tbuf[sr * 68 + eg];
      *(float4*)(td + 0) = kr0;
      *(float4*)(td + 4) = kr1;
      *(float4*)(td + 8) = kr2;
      *(float4*)(td + 12) = kr3;
    }
    __syncthreads();
    {
      const int e = tid & 63;
      const int sg = (tid >> 6) * 16;
      float v[16];
#pragma unroll
      for (int i = 0; i < 16; ++i) v[i] = tbuf[(sg + i) * 68 + e];
      float4 u0 = {v[0], v[1], v[2], v[3]},   w0 = {v[4], v[5], v[6], v[7]};
      float4 u1 = {v[8], v[9], v[10], v[11]}, w1 = {v[12], v[13], v[14], v[15]};
      uint4 h0 = pk_hi(u0, w0), h1 = pk_hi(u1, w1);
      int j0 = sg >> 3;
      char* dbase = (char*)&Bs[0][0] + e * 128;
      *(uint4*)(dbase + (((j0 + 0) ^ (e & 7)) << 4)) = h0;
      *(uint4*)(dbase + (((j0 + 1) ^ (e & 7)) << 4)) = h1;
      char* dlo = (char*)&Bs[1][0] + e * 128;
      *(uint4*)(dlo + (((j0 + 0) ^ (e & 7)) << 4)) = pk_lo(u0, w0, h0);
      *(uint4*)(dlo + (((j0 + 1) ^ (e & 7)) << 4)) = pk_lo(u1, w1, h1);
    }
    __syncthreads();
    if (k0 + 64 < kbeg + kchunk) {
      const float* ksrc = pK + (size_t)(k0 + 64 + sr) * ND + n0 + eg;
      kr0 = *(const float4*)(ksrc + 0);
      kr1 = *(const float4*)(ksrc + 4);
      kr2 = *(const float4*)(ksrc + 8);
      kr3 = *(const float4*)(ksrc + 12);
    }
#pragma unroll
    for (int kk = 0; kk < 64; kk += 32) {
      int sig = (kk >> 3) + (lane >> 4);
      bf16x8 ah[2], al[2], bh[2], bl[2];
#pragma unroll
      for (int fm = 0; fm < 2; ++fm) {
        int r = wm * 32 + fm * 16 + (lane & 15);
        int off = r * 128 + ((sig ^ (r & 7)) << 4);
        ah[fm] = *(const bf16x8*)((const char*)&As[0][0] + off);
        al[fm] = *(const bf16x8*)((const char*)&As[1][0] + off);
      }
#pragma unroll
      for (int fn = 0; fn < 2; ++fn) {
        int r = wn * 32 + fn * 16 + (lane & 15);
        int off = r * 128 + ((sig ^ (r & 7)) << 4);
        bh[fn] = *(const bf16x8*)((const char*)&Bs[0][0] + off);
        bl[fn] = *(const bf16x8*)((const char*)&Bs[1][0] + off);
      }
#pragma unroll
      for (int fm = 0; fm < 2; ++fm)
#pragma unroll
        for (int fn = 0; fn < 2; ++fn) {
          acc[fm][fn] = MFMA(ah[fm], bh[fn], acc[fm][fn]);
          acc[fm][fn] = MFMA(ah[fm], bl[fn], acc[fm][fn]);
          acc[fm][fn] = MFMA(al[fm], bh[fn], acc[fm][fn]);
        }
    }
    __syncthreads();
  }

  const int jr = lane >> 4, cl = lane & 15;
  float* pc = P + (size_t)bz * NRH * ND;
#pragma unroll
  for (int fm = 0; fm < 2; ++fm)
#pragma unroll
    for (int fn = 0; fn < 2; ++fn) {
      f32x4 v = acc[fm][fn];
      int gcol = n0 + wn * 32 + fn * 16 + cl;
#pragma unroll
      for (int j = 0; j < 4; ++j) {
        int m = m0 + wm * 32 + fm * 16 + jr * 4 + j;
        pc[(size_t)m * ND + gcol] = v[j];
      }
    }
}

// ---------------------------------------------------------------------------
// G4: lin[m][n] = sum_k ctx[m][k]*WL[n][k]; M=1536 N=1024 K=1024.
// (round-9 version: BM=64, 2-phase pipelined, 384 blocks.)
// ---------------------------------------------------------------------------
__global__ __launch_bounds__(256) void gemm_g4(
    const unsigned short* __restrict__ A, const float* __restrict__ Bf,
    float* __restrict__ lin) {
  __shared__ unsigned short As[2][64 * 64];
  __shared__ unsigned short Bs[2][64 * 64];
  const int tid = threadIdx.x;
  const int lane = tid & 63;
  const int wid = tid >> 6;
  const int wm = wid >> 1, wn = wid & 1;
  const int m0 = (blockIdx.x >> 4) * 64, n0 = (blockIdx.x & 15) * 64;
  const int rsub = lane >> 3;
  const int slotg = (lane & 7) ^ rsub;
  const int brow = tid >> 2;
  const int jbase = (tid & 3) * 2;

  f32x4 acc[2][2];
#pragma unroll
  for (int i = 0; i < 2; ++i)
#pragma unroll
    for (int j = 0; j < 2; ++j) acc[i][j] = (f32x4){0.f, 0.f, 0.f, 0.f};

#pragma unroll
  for (int cc = 0; cc < 2; ++cc) {
    int c = wid * 2 + cc;
    gload16(&A[(size_t)(m0 + c * 8 + rsub) * ND + slotg * 8], &As[0][c * 512]);
  }
  {
    const float* bsrc = Bf + (size_t)(n0 + brow) * ND + jbase * 8;
    float4 u0 = *(const float4*)(bsrc + 0), v0 = *(const float4*)(bsrc + 4);
    float4 u1 = *(const float4*)(bsrc + 8), v1 = *(const float4*)(bsrc + 12);
    char* dbase = (char*)&Bs[0][0] + brow * 128;
    *(uint4*)(dbase + (((jbase + 0) ^ (brow & 7)) << 4)) = pk_hi(u0, v0);
    *(uint4*)(dbase + (((jbase + 1) ^ (brow & 7)) << 4)) = pk_hi(u1, v1);
  }
  __syncthreads();

  int p = 0;
  for (int k0 = 0; k0 < ND; k0 += 64, p ^= 1) {
    const bool pre = (k0 + 64) < ND;
    float4 pu0 = {}, pv0 = {}, pu1 = {}, pv1 = {};
    if (pre) {
#pragma unroll
      for (int cc = 0; cc < 2; ++cc) {
        int c = wid * 2 + cc;
        gload16(&A[(size_t)(m0 + c * 8 + rsub) * ND + k0 + 64 + slotg * 8],
                &As[p ^ 1][c * 512]);
      }
      const float* bsrc = Bf + (size_t)(n0 + brow) * ND + k0 + 64 + jbase * 8;
      pu0 = *(const float4*)(bsrc + 0); pv0 = *(const float4*)(bsrc + 4);
      pu1 = *(const float4*)(bsrc + 8); pv1 = *(const float4*)(bsrc + 12);
    }
#pragma unroll
    for (int kk = 0; kk < 64; kk += 32) {
      int sig = (kk >> 3) + (lane >> 4);
      bf16x8 ah[2], bh[2];
#pragma unroll
      for (int fm = 0; fm < 2; ++fm) {
        int r = wm * 32 + fm * 16 + (lane & 15);
        int off = r * 128 + ((sig ^ (r & 7)) << 4);
        ah[fm] = *(const bf16x8*)((const char*)&As[p][0] + off);
      }
#pragma unroll
      for (int fn = 0; fn < 2; ++fn) {
        int r = wn * 32 + fn * 16 + (lane & 15);
        int off = r * 128 + ((sig ^ (r & 7)) << 4);
        bh[fn] = *(const bf16x8*)((const char*)&Bs[p][0] + off);
      }
#pragma unroll
      for (int fm = 0; fm < 2; ++fm)
#pragma unroll
        for (int fn = 0; fn < 2; ++fn)
          acc[fm][fn] = MFMA(ah[fm], bh[fn], acc[fm][fn]);
    }
    if (pre) {
      char* dbase = (char*)&Bs[p ^ 1][0] + brow * 128;
      *(uint4*)(dbase + (((jbase + 0) ^ (brow & 7)) << 4)) = pk_hi(pu0, pv0);
      *(uint4*)(dbase + (((jbase + 1) ^ (brow & 7)) << 4)) = pk_hi(pu1, pv1);
    }
    __syncthreads();
  }

  const int jr = lane >> 4, cl = lane & 15;
#pragma unroll
  for (int fm = 0; fm < 2; ++fm)
#pragma unroll
    for (int fn = 0; fn < 2; ++fn) {
      f32x4 v = acc[fm][fn];
      int gcol = n0 + wn * 32 + fn * 16 + cl;
#pragma unroll
      for (int j = 0; j < 4; ++j) {
        int m = m0 + wm * 32 + fm * 16 + jr * 4 + j;
        lin[(size_t)m * ND + gcol] = v[j];
      }
    }
}

// ---------------------------------------------------------------------------
// bias + LayerNorm -> out
// ---------------------------------------------------------------------------
__global__ __launch_bounds__(256) void bias_ln(const float* __restrict__ lin,
                                               const float* __restrict__ bias,
                                               const float* __restrict__ gamma,
                                               const float* __restrict__ beta,
                                               float* __restrict__ out) {
  int row = blockIdx.x;
  int t = threadIdx.x;
  float4 a = ((const float4*)(lin + (size_t)row * ND))[t];
  float4 bv = ((const float4*)bias)[t];
  a.x += bv.x; a.y += bv.y; a.z += bv.z; a.w += bv.w;

  float s = a.x + a.y + a.z + a.w;
  float ss = a.x * a.x + a.y * a.y + a.z * a.z + a.w * a.w;
#pragma unroll
  for (int off = 32; off > 0; off >>= 1) {
    s += __shfl_xor(s, off);
    ss += __shfl_xor(ss, off);
  }
  __shared__ float red[8];
  int wave = t >> 6, lane = t & 63;
  if (lane == 0) { red[wave] = s; red[4 + wave] = ss; }
  __syncthreads();
  s = red[0] + red[1] + red[2] + red[3];
  ss = red[4] + red[5] + red[6] + red[7];
  float mu = s * (1.0f / ND);
  float var = ss * (1.0f / ND) - mu * mu;
  float inv = rsqrtf(var + 1e-6f);
  float4 g = ((const float4*)gamma)[t];
  float4 be = ((const float4*)beta)[t];
  float4 o;
  o.x = (a.x - mu) * inv * g.x + be.x;
  o.y = (a.y - mu) * inv * g.y + be.y;
  o.z = (a.z - mu) * inv * g.z + be.z;
  o.w = (a.w - mu) * inv * g.w + be.w;
  ((float4*)(out + (size_t)row * ND))[t] = o;
}

// ---------------------------------------------------------------------------
// sm_k: one block per (b,h,r). Sums G2's split partials inline.
// ---------------------------------------------------------------------------
__global__ __launch_bounds__(256) void sm_k(const float* __restrict__ P,
                                            int nsplit,
                                            const float* __restrict__ WK,
                                            const float* __restrict__ WV,
                                            unsigned short* __restrict__ A2) {
  int x = blockIdx.x;
  int xcd = x & 7, within = x >> 3;
  int h = xcd + 8 * (within & 1);
  int rb = within >> 1;
  int r = rb >> 2, b = rb & 3;
  int idx = (b * NH + h) * NR + r;
  int rh = h * NR + r;

  const int t = threadIdx.x;
  const int lane = t & 63, wv = t >> 6;
  __shared__ float t1s[ND];
  __shared__ float s2s[NDH];
  __shared__ float attns[NDH];

  {
    const size_t sstride = (size_t)NB * NRH * ND;
    const float* base = P + ((size_t)b * NRH + rh) * ND;
    float4 a = ((const float4*)base)[t];
    for (int s = 1; s < nsplit; ++s) {
      float4 v = ((const float4*)(base + (size_t)s * sstride))[t];
      a.x += v.x; a.y += v.y; a.z += v.z; a.w += v.w;
    }
    ((float4*)t1s)[t] = a;
  }
  __syncthreads();

  for (int j = 0; j < 16; ++j) {
    int d = wv * 16 + j;
    const float* row = WK + (size_t)(h * NDH + d) * ND;
    float acc = 0.f;
#pragma unroll
    for (int i = 0; i < 16; ++i) acc += row[lane + i * 64] * t1s[lane + i * 64];
#pragma unroll
    for (int off = 32; off > 0; off >>= 1) acc += __shfl_xor(acc, off);
    if (lane == 0) s2s[d] = acc;
  }
  __syncthreads();

  if (t < NDH) {
    float s2 = s2s[t];
    float m = s2;
#pragma unroll
    for (int off = 32; off > 0; off >>= 1) m = fmaxf(m, __shfl_xor(m, off));
    float e = __expf(s2 - m);
    float sum = e;
#pragma unroll
    for (int off = 32; off > 0; off >>= 1) sum += __shfl_xor(sum, off);
    attns[t] = e / sum;
  }
  __syncthreads();

  {
    int e0 = t * 4;
    const float* wvp = WV + (size_t)h * NDH * ND + e0;
    float a0 = 0.f, a1 = 0.f, a2 = 0.f, a3 = 0.f;
#pragma unroll 4
    for (int dd = 0; dd < NDH; ++dd) {
      float4 wvv = *(const float4*)&wvp[(size_t)dd * ND];
      float a = attns[dd];
      a0 += a * wvv.x; a1 += a * wvv.y; a2 += a * wvv.z; a3 += a * wvv.w;
    }
    ushort4 o;
    o.x = rnbf(a0); o.y = rnbf(a1); o.z = rnbf(a2); o.w = rnbf(a3);
    *(ushort4*)&A2[(size_t)idx * ND + e0] = o;
  }
}

// ---------------------------------------------------------------------------
extern "C" void kernel_launch(void* const* d_in, const int* in_sizes, int n_in,
                              void* d_out, int out_size, void* d_ws, size_t ws_size,
                              hipStream_t stream) {
  const float* Q = (const float*)d_in[0];
  const float* K = (const float*)d_in[1];
  const float* V = (const float*)d_in[2];
  const float* U = (const float*)d_in[3];
  const float* WQ = (const float*)d_in[4];
  const float* WK = (const float*)d_in[5];
  const float* WV = (const float*)d_in[6];
  const float* WL = (const float*)d_in[7];
  const float* bl = (const float*)d_in[8];
  const float* ga = (const float*)d_in[9];
  const float* be = (const float*)d_in[10];
  float* out = (float*)d_out;
  char* w = (char*)d_ws;

  unsigned short* wqhi = (unsigned short*)w;
  unsigned short* wqlo = (unsigned short*)(w + 1572864);
  unsigned short* A2b = wqhi;  // reuse after G1t
  unsigned short* s1hi = (unsigned short*)(w + 3145728);
  unsigned short* s1lo = (unsigned short*)(w + 6291456);
  unsigned short* ctxb = (unsigned short*)(w + 9437184);
  float* lin = (float*)(w + 12582912);
  float* P = (float*)(w + 18874368);

  size_t avail = ws_size > 18874368 ? ws_size - 18874368 : 0;
  int sG2 = 1;
  while (sG2 * 2 <= 4 && 3145728ull * (size_t)(sG2 * 2) <= avail) sG2 *= 2;

  build_wqeff<<<NB * NH * NR, 256, 0, stream>>>(U, WQ, wqhi, wqlo);

  // G1t: s1^T, BM=64/BK=128, 384 blocks all-resident, XCD-decoded.
  gemm_tn<true><<<384, 256, 0, stream>>>(Q, wqhi, wqlo, s1hi, s1lo);

  // G2: split-K partials, fused K transpose+convert, K-reg prefetch.
  gemm_g2<<<48 * NB * sG2, 256, 0, stream>>>(s1hi, s1lo, K, P, 2048 / sG2,
                                             NB * sG2);

  // s2 -> softmax -> A2 (sums G2 partials inline)
  sm_k<<<NB * NH * NR, 256, 0, stream>>>(P, sG2, WK, WV, A2b);

  // G3t: ctx^T, BM=64/BK=128, 384 blocks, XCD-decoded.
  gemm_tn<false><<<384, 256, 0, stream>>>(V, A2b, nullptr, ctxb, nullptr);

  // G4: lin = ctx @ WL^T, BM=64, 2-phase, 384 blocks.
  gemm_g4<<<384, 256, 0, stream>>>(ctxb, WL, lin);

  // bias + LayerNorm -> out
  bias_ln<<<NB * 384, 256, 0, stream>>>(lin, bl, ga, be, out);
}

// Round 12
// 114.198 us; speedup vs baseline: 1.0799x; 1.0799x over previous
//
#include <hip/hip_runtime.h>

#define NB 4
#define NS 2048
#define ND 1024
#define NH 16
#define NDH 64
#define NR 12
#define NRH 192

typedef __attribute__((ext_vector_type(8))) short bf16x8;
typedef __attribute__((ext_vector_type(4))) float f32x4;

__device__ __forceinline__ unsigned short rnbf(float f) {
  unsigned u = __float_as_uint(f);
  u += 0x7fffu + ((u >> 16) & 1u);
  return (unsigned short)(u >> 16);
}
__device__ __forceinline__ float bf2f(unsigned short h) {
  return __uint_as_float(((unsigned)h) << 16);
}

// v_cvt_pk_bf16_f32: dst[15:0]=bf16(a) RNE, dst[31:16]=bf16(b)
__device__ __forceinline__ unsigned cvtpk(float a, float b) {
  unsigned r;
  asm("v_cvt_pk_bf16_f32 %0, %1, %2" : "=v"(r) : "v"(a), "v"(b));
  return r;
}
__device__ __forceinline__ uint4 pk_hi(float4 u, float4 w) {
  uint4 h;
  h.x = cvtpk(u.x, u.y); h.y = cvtpk(u.z, u.w);
  h.z = cvtpk(w.x, w.y); h.w = cvtpk(w.z, w.w);
  return h;
}
__device__ __forceinline__ unsigned lo2(float a, float b, unsigned hh) {
  float ah = __uint_as_float(hh << 16);
  float bh = __uint_as_float(hh & 0xffff0000u);
  return cvtpk(a - ah, b - bh);
}
__device__ __forceinline__ uint4 pk_lo(float4 u, float4 w, uint4 h) {
  uint4 l;
  l.x = lo2(u.x, u.y, h.x); l.y = lo2(u.z, u.w, h.y);
  l.z = lo2(w.x, w.y, h.z); l.w = lo2(w.z, w.w, h.w);
  return l;
}

__device__ __forceinline__ void gload16(const void* g, void* l) {
  __builtin_amdgcn_global_load_lds(
      (const __attribute__((address_space(1))) unsigned int*)g,
      (__attribute__((address_space(3))) unsigned int*)l, 16, 0, 0);
}

#define MFMA(a, b, c) __builtin_amdgcn_mfma_f32_16x16x32_bf16(a, b, c, 0, 0, 0)

// ---------------------------------------------------------------------------
// Wq_eff[b,h,r,e] = sum_d U[b,h,r,d] * W_Q[h*64+d, e]  -> hi/lo bf16
// ---------------------------------------------------------------------------
__global__ __launch_bounds__(256) void build_wqeff(const float* __restrict__ U,
                                                   const float* __restrict__ WQ,
                                                   unsigned short* __restrict__ wqhi,
                                                   unsigned short* __restrict__ wqlo) {
  int idx = blockIdx.x;
  int hr = idx % (NH * NR);
  int h = hr / NR;
  __shared__ float u[NDH];
  int t = threadIdx.x;
  if (t < NDH) u[t] = U[(size_t)idx * NDH + t];
  __syncthreads();
  int e0 = t * 4;
  float a0 = 0.f, a1 = 0.f, a2 = 0.f, a3 = 0.f;
  const float* wbase = WQ + (size_t)h * NDH * ND + e0;
#pragma unroll 4
  for (int d = 0; d < NDH; ++d) {
    float uv = u[d];
    const float* wr = wbase + (size_t)d * ND;
    a0 += uv * wr[0]; a1 += uv * wr[1]; a2 += uv * wr[2]; a3 += uv * wr[3];
  }
  ushort4 h4, l4;
  h4.x = rnbf(a0); l4.x = rnbf(a0 - bf2f(h4.x));
  h4.y = rnbf(a1); l4.y = rnbf(a1 - bf2f(h4.y));
  h4.z = rnbf(a2); l4.z = rnbf(a2 - bf2f(h4.z));
  h4.w = rnbf(a3); l4.w = rnbf(a3 - bf2f(h4.w));
  *(ushort4*)&wqhi[(size_t)idx * ND + e0] = h4;
  *(ushort4*)&wqlo[(size_t)idx * ND + e0] = l4;
}

// ---------------------------------------------------------------------------
// gemm_tn: C^T-oriented GEMM, 2-phase pipelined (dbuf LDS, 1 barrier/iter),
// XCD-aware decode. BM=32, BK=64, 768 blocks (3/CU). [round-9 best config]
// ---------------------------------------------------------------------------
template <bool PAIR>
__global__ __launch_bounds__(256) void gemm_tn(
    const float* __restrict__ Af,
    const unsigned short* __restrict__ Bhi, const unsigned short* __restrict__ Blo,
    unsigned short* __restrict__ C0, unsigned short* __restrict__ C1) {
  constexpr int NBUF = PAIR ? 2 : 1;
  __shared__ unsigned short As[2][NBUF][32 * 64];
  __shared__ unsigned short Bs[2][NBUF][64 * 64];
  const int tid = threadIdx.x;
  const int lane = tid & 63;
  const int wid = tid >> 6;
  const int wm = wid >> 1, wn = wid & 1;

  int lin = blockIdx.x;
  int xcd = lin & 7, slot = lin >> 3;   // slot 0..95
  int b = slot / 24;
  int rem = slot % 24;
  int m0 = ((rem / 3) * 8 + xcd) * 32;  // 0..2016
  int n0 = (rem % 3) * 64;

  const float* pA = Af + (size_t)b * NS * ND;
  const unsigned short* pBhi = Bhi + (size_t)b * NRH * ND;
  const unsigned short* pBlo = PAIR ? Blo + (size_t)b * NRH * ND : nullptr;

  const int rsub = lane >> 3;
  const int slotg = (lane & 7) ^ rsub;
  const int arow = tid >> 3;  // 0..31
  const int jg = tid & 7;     // slot 0..7

  f32x4 acc[2];
  acc[0] = (f32x4){0.f, 0.f, 0.f, 0.f};
  acc[1] = (f32x4){0.f, 0.f, 0.f, 0.f};

  // prologue: stage tile 0 into buffer 0
  {
    const float* asrc = pA + (size_t)(m0 + arow) * ND + jg * 8;
    float4 au = *(const float4*)(asrc);
    float4 av = *(const float4*)(asrc + 4);
#pragma unroll
    for (int cc = 0; cc < 2; ++cc) {
      int c = wid * 2 + cc;
      int grow = n0 + c * 8 + rsub;
      gload16(&pBhi[(size_t)grow * ND + slotg * 8], &Bs[0][0][c * 512]);
      if (PAIR)
        gload16(&pBlo[(size_t)grow * ND + slotg * 8], &Bs[0][NBUF - 1][c * 512]);
    }
    uint4 h = pk_hi(au, av);
    char* dst = (char*)&As[0][0][0] + arow * 128 + ((jg ^ (arow & 7)) << 4);
    *(uint4*)dst = h;
    if (PAIR) *(uint4*)(dst + 4096) = pk_lo(au, av, h);
  }
  __syncthreads();

  int p = 0;
  for (int k0 = 0; k0 < ND; k0 += 64, p ^= 1) {
    const bool pre = (k0 + 64) < ND;
    float4 aun = {}, avn = {};
    if (pre) {
      const float* asrc = pA + (size_t)(m0 + arow) * ND + k0 + 64 + jg * 8;
      aun = *(const float4*)(asrc);
      avn = *(const float4*)(asrc + 4);
#pragma unroll
      for (int cc = 0; cc < 2; ++cc) {
        int c = wid * 2 + cc;
        int grow = n0 + c * 8 + rsub;
        gload16(&pBhi[(size_t)grow * ND + k0 + 64 + slotg * 8],
                &Bs[p ^ 1][0][c * 512]);
        if (PAIR)
          gload16(&pBlo[(size_t)grow * ND + k0 + 64 + slotg * 8],
                  &Bs[p ^ 1][NBUF - 1][c * 512]);
      }
    }
#pragma unroll
    for (int kk = 0; kk < 64; kk += 32) {
      int sig = (kk >> 3) + (lane >> 4);
      bf16x8 ah, al, bh[2], bl[2];
      {
        int r = wm * 16 + (lane & 15);
        int off = r * 128 + ((sig ^ (r & 7)) << 4);
        ah = *(const bf16x8*)((const char*)&As[p][0][0] + off);
        if (PAIR) al = *(const bf16x8*)((const char*)&As[p][NBUF - 1][0] + off);
      }
#pragma unroll
      for (int fn = 0; fn < 2; ++fn) {
        int r = wn * 32 + fn * 16 + (lane & 15);
        int off = r * 128 + ((sig ^ (r & 7)) << 4);
        bh[fn] = *(const bf16x8*)((const char*)&Bs[p][0][0] + off);
        if (PAIR)
          bl[fn] = *(const bf16x8*)((const char*)&Bs[p][NBUF - 1][0] + off);
      }
#pragma unroll
      for (int fn = 0; fn < 2; ++fn) {
        acc[fn] = MFMA(ah, bh[fn], acc[fn]);
        if (PAIR) {
          acc[fn] = MFMA(ah, bl[fn], acc[fn]);
          acc[fn] = MFMA(al, bh[fn], acc[fn]);
        }
      }
    }
    if (pre) {
      uint4 h = pk_hi(aun, avn);
      char* dst =
          (char*)&As[p ^ 1][0][0] + arow * 128 + ((jg ^ (arow & 7)) << 4);
      *(uint4*)dst = h;
      if (PAIR) *(uint4*)(dst + 4096) = pk_lo(aun, avn, h);
    }
    __syncthreads();
  }

  const int jr = lane >> 4, cl = lane & 15;
#pragma unroll
  for (int fn = 0; fn < 2; ++fn) {
    f32x4 v = acc[fn];
    int s = m0 + wm * 16 + jr * 4;
    int rh = n0 + wn * 32 + fn * 16 + cl;
    int orow = PAIR ? rh : (rh % NR) * NH + rh / NR;
    size_t o = ((size_t)b * NRH + orow) * NS + s;
    ushort4 h4;
    h4.x = rnbf(v[0]); h4.y = rnbf(v[1]);
    h4.z = rnbf(v[2]); h4.w = rnbf(v[3]);
    *(ushort4*)&C0[o] = h4;
    if (PAIR) {
      ushort4 l4;
      l4.x = rnbf(v[0] - bf2f(h4.x)); l4.y = rnbf(v[1] - bf2f(h4.y));
      l4.z = rnbf(v[2] - bf2f(h4.z)); l4.w = rnbf(v[3] - bf2f(h4.w));
      *(ushort4*)&C1[o] = l4;
    }
  }
}

// ---------------------------------------------------------------------------
// G2: T1 partials. P[z][m][e] = sum_{s in chunk z} s1[m][s]*K[s][e]
// hi/lo pair; in-kernel K transpose+convert; K-reg prefetch; XCD decode.
// ---------------------------------------------------------------------------
__global__ __launch_bounds__(256) void gemm_g2(
    const unsigned short* __restrict__ Ahi, const unsigned short* __restrict__ Alo,
    const float* __restrict__ Kf, float* __restrict__ P,
    int kchunk, int nz) {
  __shared__ unsigned short As[2][64 * 64];
  __shared__ unsigned short Bs[2][64 * 64];
  __shared__ float tbuf[64 * 68];
  const int tid = threadIdx.x;
  const int lane = tid & 63;
  const int wid = tid >> 6;
  const int wm = wid >> 1, wn = wid & 1;

  int lin = blockIdx.x;
  int bz, m_idx, n_idx;
  if (nz == 16) {
    int xcd = lin & 7, slot = lin >> 3;
    bz = xcd + 8 * (slot / 48);
    int rem = slot % 48;
    m_idx = rem / 16; n_idx = rem % 16;
  } else {
    bz = lin / 48;
    int rem = lin % 48;
    m_idx = rem / 16; n_idx = rem % 16;
  }
  const int m0 = m_idx * 64, n0 = n_idx * 64;
  const int b = bz % NB;
  const int kbeg = (bz / NB) * kchunk;
  const unsigned short* pAhi = Ahi + (size_t)b * NRH * NS;
  const unsigned short* pAlo = Alo + (size_t)b * NRH * NS;
  const float* pK = Kf + (size_t)b * NS * ND;

  const int rsub = lane >> 3;
  const int slotg = (lane & 7) ^ rsub;
  const int sr = tid >> 2;
  const int eg = (tid & 3) * 16;

  f32x4 acc[2][2];
#pragma unroll
  for (int i = 0; i < 2; ++i)
#pragma unroll
    for (int j = 0; j < 2; ++j) acc[i][j] = (f32x4){0.f, 0.f, 0.f, 0.f};

  float4 kr0, kr1, kr2, kr3;
  {
    const float* ksrc = pK + (size_t)(kbeg + sr) * ND + n0 + eg;
    kr0 = *(const float4*)(ksrc + 0);
    kr1 = *(const float4*)(ksrc + 4);
    kr2 = *(const float4*)(ksrc + 8);
    kr3 = *(const float4*)(ksrc + 12);
  }

  for (int k0 = kbeg; k0 < kbeg + kchunk; k0 += 64) {
#pragma unroll
    for (int cc = 0; cc < 2; ++cc) {
      int c = wid * 2 + cc;
      int grow = m0 + c * 8 + rsub;
      gload16(&pAhi[(size_t)grow * NS + k0 + slotg * 8], &As[0][c * 512]);
      gload16(&pAlo[(size_t)grow * NS + k0 + slotg * 8], &As[1][c * 512]);
    }
    {
      float* td = &tbuf[sr * 68 + eg];
      *(float4*)(td + 0) = kr0;
      *(float4*)(td + 4) = kr1;
      *(float4*)(td + 8) = kr2;
      *(float4*)(td + 12) = kr3;
    }
    __syncthreads();
    {
      const int e = tid & 63;
      const int sg = (tid >> 6) * 16;
      float v[16];
#pragma unroll
      for (int i = 0; i < 16; ++i) v[i] = tbuf[(sg + i) * 68 + e];
      float4 u0 = {v[0], v[1], v[2], v[3]},   w0 = {v[4], v[5], v[6], v[7]};
      float4 u1 = {v[8], v[9], v[10], v[11]}, w1 = {v[12], v[13], v[14], v[15]};
      uint4 h0 = pk_hi(u0, w0), h1 = pk_hi(u1, w1);
      int j0 = sg >> 3;
      char* dbase = (char*)&Bs[0][0] + e * 128;
      *(uint4*)(dbase + (((j0 + 0) ^ (e & 7)) << 4)) = h0;
      *(uint4*)(dbase + (((j0 + 1) ^ (e & 7)) << 4)) = h1;
      char* dlo = (char*)&Bs[1][0] + e * 128;
      *(uint4*)(dlo + (((j0 + 0) ^ (e & 7)) << 4)) = pk_lo(u0, w0, h0);
      *(uint4*)(dlo + (((j0 + 1) ^ (e & 7)) << 4)) = pk_lo(u1, w1, h1);
    }
    __syncthreads();
    if (k0 + 64 < kbeg + kchunk) {
      const float* ksrc = pK + (size_t)(k0 + 64 + sr) * ND + n0 + eg;
      kr0 = *(const float4*)(ksrc + 0);
      kr1 = *(const float4*)(ksrc + 4);
      kr2 = *(const float4*)(ksrc + 8);
      kr3 = *(const float4*)(ksrc + 12);
    }
#pragma unroll
    for (int kk = 0; kk < 64; kk += 32) {
      int sig = (kk >> 3) + (lane >> 4);
      bf16x8 ah[2], al[2], bh[2], bl[2];
#pragma unroll
      for (int fm = 0; fm < 2; ++fm) {
        int r = wm * 32 + fm * 16 + (lane & 15);
        int off = r * 128 + ((sig ^ (r & 7)) << 4);
        ah[fm] = *(const bf16x8*)((const char*)&As[0][0] + off);
        al[fm] = *(const bf16x8*)((const char*)&As[1][0] + off);
      }
#pragma unroll
      for (int fn = 0; fn < 2; ++fn) {
        int r = wn * 32 + fn * 16 + (lane & 15);
        int off = r * 128 + ((sig ^ (r & 7)) << 4);
        bh[fn] = *(const bf16x8*)((const char*)&Bs[0][0] + off);
        bl[fn] = *(const bf16x8*)((const char*)&Bs[1][0] + off);
      }
#pragma unroll
      for (int fm = 0; fm < 2; ++fm)
#pragma unroll
        for (int fn = 0; fn < 2; ++fn) {
          acc[fm][fn] = MFMA(ah[fm], bh[fn], acc[fm][fn]);
          acc[fm][fn] = MFMA(ah[fm], bl[fn], acc[fm][fn]);
          acc[fm][fn] = MFMA(al[fm], bh[fn], acc[fm][fn]);
        }
    }
    __syncthreads();
  }

  const int jr = lane >> 4, cl = lane & 15;
  float* pc = P + (size_t)bz * NRH * ND;
#pragma unroll
  for (int fm = 0; fm < 2; ++fm)
#pragma unroll
    for (int fn = 0; fn < 2; ++fn) {
      f32x4 v = acc[fm][fn];
      int gcol = n0 + wn * 32 + fn * 16 + cl;
#pragma unroll
      for (int j = 0; j < 4; ++j) {
        int m = m0 + wm * 32 + fm * 16 + jr * 4 + j;
        pc[(size_t)m * ND + gcol] = v[j];
      }
    }
}

// ---------------------------------------------------------------------------
// G4: lin[m][n] = sum_k ctx[m][k]*WL[n][k]; BM=64, 2-phase, 384 blocks.
// ---------------------------------------------------------------------------
__global__ __launch_bounds__(256) void gemm_g4(
    const unsigned short* __restrict__ A, const float* __restrict__ Bf,
    float* __restrict__ lin) {
  __shared__ unsigned short As[2][64 * 64];
  __shared__ unsigned short Bs[2][64 * 64];
  const int tid = threadIdx.x;
  const int lane = tid & 63;
  const int wid = tid >> 6;
  const int wm = wid >> 1, wn = wid & 1;
  const int m0 = (blockIdx.x >> 4) * 64, n0 = (blockIdx.x & 15) * 64;
  const int rsub = lane >> 3;
  const int slotg = (lane & 7) ^ rsub;
  const int brow = tid >> 2;
  const int jbase = (tid & 3) * 2;

  f32x4 acc[2][2];
#pragma unroll
  for (int i = 0; i < 2; ++i)
#pragma unroll
    for (int j = 0; j < 2; ++j) acc[i][j] = (f32x4){0.f, 0.f, 0.f, 0.f};

#pragma unroll
  for (int cc = 0; cc < 2; ++cc) {
    int c = wid * 2 + cc;
    gload16(&A[(size_t)(m0 + c * 8 + rsub) * ND + slotg * 8], &As[0][c * 512]);
  }
  {
    const float* bsrc = Bf + (size_t)(n0 + brow) * ND + jbase * 8;
    float4 u0 = *(const float4*)(bsrc + 0), v0 = *(const float4*)(bsrc + 4);
    float4 u1 = *(const float4*)(bsrc + 8), v1 = *(const float4*)(bsrc + 12);
    char* dbase = (char*)&Bs[0][0] + brow * 128;
    *(uint4*)(dbase + (((jbase + 0) ^ (brow & 7)) << 4)) = pk_hi(u0, v0);
    *(uint4*)(dbase + (((jbase + 1) ^ (brow & 7)) << 4)) = pk_hi(u1, v1);
  }
  __syncthreads();

  int p = 0;
  for (int k0 = 0; k0 < ND; k0 += 64, p ^= 1) {
    const bool pre = (k0 + 64) < ND;
    float4 pu0 = {}, pv0 = {}, pu1 = {}, pv1 = {};
    if (pre) {
#pragma unroll
      for (int cc = 0; cc < 2; ++cc) {
        int c = wid * 2 + cc;
        gload16(&A[(size_t)(m0 + c * 8 + rsub) * ND + k0 + 64 + slotg * 8],
                &As[p ^ 1][c * 512]);
      }
      const float* bsrc = Bf + (size_t)(n0 + brow) * ND + k0 + 64 + jbase * 8;
      pu0 = *(const float4*)(bsrc + 0); pv0 = *(const float4*)(bsrc + 4);
      pu1 = *(const float4*)(bsrc + 8); pv1 = *(const float4*)(bsrc + 12);
    }
#pragma unroll
    for (int kk = 0; kk < 64; kk += 32) {
      int sig = (kk >> 3) + (lane >> 4);
      bf16x8 ah[2], bh[2];
#pragma unroll
      for (int fm = 0; fm < 2; ++fm) {
        int r = wm * 32 + fm * 16 + (lane & 15);
        int off = r * 128 + ((sig ^ (r & 7)) << 4);
        ah[fm] = *(const bf16x8*)((const char*)&As[p][0] + off);
      }
#pragma unroll
      for (int fn = 0; fn < 2; ++fn) {
        int r = wn * 32 + fn * 16 + (lane & 15);
        int off = r * 128 + ((sig ^ (r & 7)) << 4);
        bh[fn] = *(const bf16x8*)((const char*)&Bs[p][0] + off);
      }
#pragma unroll
      for (int fm = 0; fm < 2; ++fm)
#pragma unroll
        for (int fn = 0; fn < 2; ++fn)
          acc[fm][fn] = MFMA(ah[fm], bh[fn], acc[fm][fn]);
    }
    if (pre) {
      char* dbase = (char*)&Bs[p ^ 1][0] + brow * 128;
      *(uint4*)(dbase + (((jbase + 0) ^ (brow & 7)) << 4)) = pk_hi(pu0, pv0);
      *(uint4*)(dbase + (((jbase + 1) ^ (brow & 7)) << 4)) = pk_hi(pu1, pv1);
    }
    __syncthreads();
  }

  const int jr = lane >> 4, cl = lane & 15;
#pragma unroll
  for (int fm = 0; fm < 2; ++fm)
#pragma unroll
    for (int fn = 0; fn < 2; ++fn) {
      f32x4 v = acc[fm][fn];
      int gcol = n0 + wn * 32 + fn * 16 + cl;
#pragma unroll
      for (int j = 0; j < 4; ++j) {
        int m = m0 + wm * 32 + fm * 16 + jr * 4 + j;
        lin[(size_t)m * ND + gcol] = v[j];
      }
    }
}

// ---------------------------------------------------------------------------
// bias + LayerNorm -> out
// ---------------------------------------------------------------------------
__global__ __launch_bounds__(256) void bias_ln(const float* __restrict__ lin,
                                               const float* __restrict__ bias,
                                               const float* __restrict__ gamma,
                                               const float* __restrict__ beta,
                                               float* __restrict__ out) {
  int row = blockIdx.x;
  int t = threadIdx.x;
  float4 a = ((const float4*)(lin + (size_t)row * ND))[t];
  float4 bv = ((const float4*)bias)[t];
  a.x += bv.x; a.y += bv.y; a.z += bv.z; a.w += bv.w;

  float s = a.x + a.y + a.z + a.w;
  float ss = a.x * a.x + a.y * a.y + a.z * a.z + a.w * a.w;
#pragma unroll
  for (int off = 32; off > 0; off >>= 1) {
    s += __shfl_xor(s, off);
    ss += __shfl_xor(ss, off);
  }
  __shared__ float red[8];
  int wave = t >> 6, lane = t & 63;
  if (lane == 0) { red[wave] = s; red[4 + wave] = ss; }
  __syncthreads();
  s = red[0] + red[1] + red[2] + red[3];
  ss = red[4] + red[5] + red[6] + red[7];
  float mu = s * (1.0f / ND);
  float var = ss * (1.0f / ND) - mu * mu;
  float inv = rsqrtf(var + 1e-6f);
  float4 g = ((const float4*)gamma)[t];
  float4 be = ((const float4*)beta)[t];
  float4 o;
  o.x = (a.x - mu) * inv * g.x + be.x;
  o.y = (a.y - mu) * inv * g.y + be.y;
  o.z = (a.z - mu) * inv * g.z + be.z;
  o.w = (a.w - mu) * inv * g.w + be.w;
  ((float4*)(out + (size_t)row * ND))[t] = o;
}

// ---------------------------------------------------------------------------
// sm_k2: one block per (b,h,rhalf): 128 blocks x 512 threads, 6 r-rows each.
// WK/WV head slices read ONCE per block (was once per (b,h,r) -> 6x less L2).
// Phase ops and summation order identical to prior sm_k -> same numerics.
// ---------------------------------------------------------------------------
__global__ __launch_bounds__(512) void sm_k2(const float* __restrict__ P,
                                             int nsplit,
                                             const float* __restrict__ WK,
                                             const float* __restrict__ WV,
                                             unsigned short* __restrict__ A2) {
  int x = blockIdx.x;  // 0..127
  int h = (x & 7) + 8 * ((x >> 3) & 1);
  int rhalf = (x >> 4) & 1;
  int b = x >> 5;

  const int t = threadIdx.x;
  const int lane = t & 63, wv = t >> 6;  // 8 waves
  __shared__ float t1s[6][ND];
  __shared__ float s2s[6][NDH];
  __shared__ float attns[6][NDH];

  // phase 1: sum split partials for rows rh = h*12 + rhalf*6 + rr
  {
    const size_t sstride = (size_t)NB * NRH * ND;
    for (int i = t; i < 6 * 256; i += 512) {
      int rr = i >> 8;
      int c4 = i & 255;
      int rh = h * NR + rhalf * 6 + rr;
      const float* base = P + ((size_t)b * NRH + rh) * ND;
      float4 a = ((const float4*)base)[c4];
      for (int s = 1; s < nsplit; ++s) {
        float4 v = ((const float4*)(base + (size_t)s * sstride))[c4];
        a.x += v.x; a.y += v.y; a.z += v.z; a.w += v.w;
      }
      ((float4*)t1s[rr])[c4] = a;
    }
  }
  __syncthreads();

  // phase 2: s2[rr][d], d = wv*8 + j; WK row loaded once per d
  for (int j = 0; j < 8; ++j) {
    int d = wv * 8 + j;
    const float* row = WK + (size_t)(h * NDH + d) * ND;
    float rw[16];
#pragma unroll
    for (int i = 0; i < 16; ++i) rw[i] = row[lane + i * 64];
#pragma unroll
    for (int rr = 0; rr < 6; ++rr) {
      float acc = 0.f;
#pragma unroll
      for (int i = 0; i < 16; ++i) acc += rw[i] * t1s[rr][lane + i * 64];
#pragma unroll
      for (int off = 32; off > 0; off >>= 1) acc += __shfl_xor(acc, off);
      if (lane == 0) s2s[rr][d] = acc;
    }
  }
  __syncthreads();

  // phase 3: softmax over d=64, wave rr handles row rr (rr<6)
  if (wv < 6) {
    float v = s2s[wv][lane];
    float m = v;
#pragma unroll
    for (int off = 32; off > 0; off >>= 1) m = fmaxf(m, __shfl_xor(m, off));
    float e = __expf(v - m);
    float sum = e;
#pragma unroll
    for (int off = 32; off > 0; off >>= 1) sum += __shfl_xor(sum, off);
    attns[wv][lane] = e / sum;
  }
  __syncthreads();

  // phase 4: A2 rows; thread owns e0, 3 r-rows; WV read once per block
  {
    int e0 = (t & 255) * 4;
    int rg = t >> 8;  // 0 or 1
    const float* wvp = WV + (size_t)h * NDH * ND + e0;
    float acc[3][4];
#pragma unroll
    for (int q = 0; q < 3; ++q) {
      acc[q][0] = 0.f; acc[q][1] = 0.f; acc[q][2] = 0.f; acc[q][3] = 0.f;
    }
#pragma unroll 4
    for (int dd = 0; dd < NDH; ++dd) {
      float4 w4 = *(const float4*)&wvp[(size_t)dd * ND];
#pragma unroll
      for (int q = 0; q < 3; ++q) {
        float a = attns[rg * 3 + q][dd];
        acc[q][0] += a * w4.x; acc[q][1] += a * w4.y;
        acc[q][2] += a * w4.z; acc[q][3] += a * w4.w;
      }
    }
#pragma unroll
    for (int q = 0; q < 3; ++q) {
      int idx = (b * NH + h) * NR + rhalf * 6 + rg * 3 + q;
      ushort4 o;
      o.x = rnbf(acc[q][0]); o.y = rnbf(acc[q][1]);
      o.z = rnbf(acc[q][2]); o.w = rnbf(acc[q][3]);
      *(ushort4*)&A2[(size_t)idx * ND + e0] = o;
    }
  }
}

// ---------------------------------------------------------------------------
extern "C" void kernel_launch(void* const* d_in, const int* in_sizes, int n_in,
                              void* d_out, int out_size, void* d_ws, size_t ws_size,
                              hipStream_t stream) {
  const float* Q = (const float*)d_in[0];
  const float* K = (const float*)d_in[1];
  const float* V = (const float*)d_in[2];
  const float* U = (const float*)d_in[3];
  const float* WQ = (const float*)d_in[4];
  const float* WK = (const float*)d_in[5];
  const float* WV = (const float*)d_in[6];
  const float* WL = (const float*)d_in[7];
  const float* bl = (const float*)d_in[8];
  const float* ga = (const float*)d_in[9];
  const float* be = (const float*)d_in[10];
  float* out = (float*)d_out;
  char* w = (char*)d_ws;

  unsigned short* wqhi = (unsigned short*)w;
  unsigned short* wqlo = (unsigned short*)(w + 1572864);
  unsigned short* A2b = wqhi;  // reuse after G1t
  unsigned short* s1hi = (unsigned short*)(w + 3145728);
  unsigned short* s1lo = (unsigned short*)(w + 6291456);
  unsigned short* ctxb = (unsigned short*)(w + 9437184);
  float* lin = (float*)(w + 12582912);
  float* P = (float*)(w + 18874368);

  size_t avail = ws_size > 18874368 ? ws_size - 18874368 : 0;
  int sG2 = 1;
  while (sG2 * 2 <= 4 && 3145728ull * (size_t)(sG2 * 2) <= avail) sG2 *= 2;

  build_wqeff<<<NB * NH * NR, 256, 0, stream>>>(U, WQ, wqhi, wqlo);

  // G1t: s1^T, BM=32, 768 blocks, 2-phase, XCD-decoded.
  gemm_tn<true><<<768, 256, 0, stream>>>(Q, wqhi, wqlo, s1hi, s1lo);

  // G2: split-K partials, fused K transpose+convert, K-reg prefetch.
  gemm_g2<<<48 * NB * sG2, 256, 0, stream>>>(s1hi, s1lo, K, P, 2048 / sG2,
                                             NB * sG2);

  // s2 -> softmax -> A2 (sums G2 partials inline); 128 blocks x 512 thr
  sm_k2<<<128, 512, 0, stream>>>(P, sG2, WK, WV, A2b);

  // G3t: ctx^T, BM=32, 768 blocks, 2-phase, XCD-decoded.
  gemm_tn<false><<<768, 256, 0, stream>>>(V, A2b, nullptr, ctxb, nullptr);

  // G4: lin = ctx @ WL^T, BM=64, 2-phase, 384 blocks.
  gemm_g4<<<384, 256, 0, stream>>>(ctxb, WL, lin);

  // bias + LayerNorm -> out
  bias_ln<<<NB * 384, 256, 0, stream>>>(lin, bl, ga, be, out);
}

// Round 13
// 107.678 us; speedup vs baseline: 1.1453x; 1.0606x over previous
//
#include <hip/hip_runtime.h>

#define NB 4
#define NS 2048
#define ND 1024
#define NH 16
#define NDH 64
#define NR 12
#define NRH 192

typedef __attribute__((ext_vector_type(8))) short bf16x8;
typedef __attribute__((ext_vector_type(4))) float f32x4;

__device__ __forceinline__ unsigned short rnbf(float f) {
  unsigned u = __float_as_uint(f);
  u += 0x7fffu + ((u >> 16) & 1u);
  return (unsigned short)(u >> 16);
}
__device__ __forceinline__ float bf2f(unsigned short h) {
  return __uint_as_float(((unsigned)h) << 16);
}

// v_cvt_pk_bf16_f32: dst[15:0]=bf16(a) RNE, dst[31:16]=bf16(b)
__device__ __forceinline__ unsigned cvtpk(float a, float b) {
  unsigned r;
  asm("v_cvt_pk_bf16_f32 %0, %1, %2" : "=v"(r) : "v"(a), "v"(b));
  return r;
}
__device__ __forceinline__ uint4 pk_hi(float4 u, float4 w) {
  uint4 h;
  h.x = cvtpk(u.x, u.y); h.y = cvtpk(u.z, u.w);
  h.z = cvtpk(w.x, w.y); h.w = cvtpk(w.z, w.w);
  return h;
}
__device__ __forceinline__ unsigned lo2(float a, float b, unsigned hh) {
  float ah = __uint_as_float(hh << 16);
  float bh = __uint_as_float(hh & 0xffff0000u);
  return cvtpk(a - ah, b - bh);
}
__device__ __forceinline__ uint4 pk_lo(float4 u, float4 w, uint4 h) {
  uint4 l;
  l.x = lo2(u.x, u.y, h.x); l.y = lo2(u.z, u.w, h.y);
  l.z = lo2(w.x, w.y, h.z); l.w = lo2(w.z, w.w, h.w);
  return l;
}

__device__ __forceinline__ void gload16(const void* g, void* l) {
  __builtin_amdgcn_global_load_lds(
      (const __attribute__((address_space(1))) unsigned int*)g,
      (__attribute__((address_space(3))) unsigned int*)l, 16, 0, 0);
}

#define MFMA(a, b, c) __builtin_amdgcn_mfma_f32_16x16x32_bf16(a, b, c, 0, 0, 0)

// ---------------------------------------------------------------------------
// Wq_eff[b,h,r,e] = sum_d U[b,h,r,d] * W_Q[h*64+d, e]  -> hi/lo bf16
// ---------------------------------------------------------------------------
__global__ __launch_bounds__(256) void build_wqeff(const float* __restrict__ U,
                                                   const float* __restrict__ WQ,
                                                   unsigned short* __restrict__ wqhi,
                                                   unsigned short* __restrict__ wqlo) {
  int idx = blockIdx.x;
  int hr = idx % (NH * NR);
  int h = hr / NR;
  __shared__ float u[NDH];
  int t = threadIdx.x;
  if (t < NDH) u[t] = U[(size_t)idx * NDH + t];
  __syncthreads();
  int e0 = t * 4;
  float a0 = 0.f, a1 = 0.f, a2 = 0.f, a3 = 0.f;
  const float* wbase = WQ + (size_t)h * NDH * ND + e0;
#pragma unroll 4
  for (int d = 0; d < NDH; ++d) {
    float uv = u[d];
    const float* wr = wbase + (size_t)d * ND;
    a0 += uv * wr[0]; a1 += uv * wr[1]; a2 += uv * wr[2]; a3 += uv * wr[3];
  }
  ushort4 h4, l4;
  h4.x = rnbf(a0); l4.x = rnbf(a0 - bf2f(h4.x));
  h4.y = rnbf(a1); l4.y = rnbf(a1 - bf2f(h4.y));
  h4.z = rnbf(a2); l4.z = rnbf(a2 - bf2f(h4.z));
  h4.w = rnbf(a3); l4.w = rnbf(a3 - bf2f(h4.w));
  *(ushort4*)&wqhi[(size_t)idx * ND + e0] = h4;
  *(ushort4*)&wqlo[(size_t)idx * ND + e0] = l4;
}

// ---------------------------------------------------------------------------
// gemm_tn: C^T-oriented GEMM, 2-phase pipelined (dbuf LDS, 1 barrier/iter),
// XCD-aware decode (trio of n-blocks sharing an m0 co-located per XCD).
//   out[n][m] = sum_k A[m][k]*B[n][k]; M=2048(s), N=192(rh), K=1024; BM=32.
// A = fp32 reg-staged to bf16 (pair iff PAIR); B = bf16 via global_load_lds.
// grid: 768 blocks (1D).  [round-9 best config: 107.76 us total]
// ---------------------------------------------------------------------------
template <bool PAIR>
__global__ __launch_bounds__(256) void gemm_tn(
    const float* __restrict__ Af,
    const unsigned short* __restrict__ Bhi, const unsigned short* __restrict__ Blo,
    unsigned short* __restrict__ C0, unsigned short* __restrict__ C1) {
  constexpr int NBUF = PAIR ? 2 : 1;
  __shared__ unsigned short As[2][NBUF][32 * 64];
  __shared__ unsigned short Bs[2][NBUF][64 * 64];
  const int tid = threadIdx.x;
  const int lane = tid & 63;
  const int wid = tid >> 6;
  const int wm = wid >> 1, wn = wid & 1;

  int lin = blockIdx.x;
  int xcd = lin & 7, slot = lin >> 3;   // slot 0..95
  int b = slot / 24;
  int rem = slot % 24;
  int m0 = ((rem / 3) * 8 + xcd) * 32;  // 0..2016
  int n0 = (rem % 3) * 64;

  const float* pA = Af + (size_t)b * NS * ND;
  const unsigned short* pBhi = Bhi + (size_t)b * NRH * ND;
  const unsigned short* pBlo = PAIR ? Blo + (size_t)b * NRH * ND : nullptr;

  const int rsub = lane >> 3;
  const int slotg = (lane & 7) ^ rsub;
  const int arow = tid >> 3;  // 0..31
  const int jg = tid & 7;     // slot 0..7

  f32x4 acc[2];
  acc[0] = (f32x4){0.f, 0.f, 0.f, 0.f};
  acc[1] = (f32x4){0.f, 0.f, 0.f, 0.f};

  // prologue: stage tile 0 into buffer 0
  {
    const float* asrc = pA + (size_t)(m0 + arow) * ND + jg * 8;
    float4 au = *(const float4*)(asrc);
    float4 av = *(const float4*)(asrc + 4);
#pragma unroll
    for (int cc = 0; cc < 2; ++cc) {
      int c = wid * 2 + cc;
      int grow = n0 + c * 8 + rsub;
      gload16(&pBhi[(size_t)grow * ND + slotg * 8], &Bs[0][0][c * 512]);
      if (PAIR)
        gload16(&pBlo[(size_t)grow * ND + slotg * 8], &Bs[0][NBUF - 1][c * 512]);
    }
    uint4 h = pk_hi(au, av);
    char* dst = (char*)&As[0][0][0] + arow * 128 + ((jg ^ (arow & 7)) << 4);
    *(uint4*)dst = h;
    if (PAIR) *(uint4*)(dst + 4096) = pk_lo(au, av, h);
  }
  __syncthreads();

  int p = 0;
  for (int k0 = 0; k0 < ND; k0 += 64, p ^= 1) {
    const bool pre = (k0 + 64) < ND;
    float4 aun = {}, avn = {};
    if (pre) {
      // issue next-tile loads: in flight during this tile's MFMA
      const float* asrc = pA + (size_t)(m0 + arow) * ND + k0 + 64 + jg * 8;
      aun = *(const float4*)(asrc);
      avn = *(const float4*)(asrc + 4);
#pragma unroll
      for (int cc = 0; cc < 2; ++cc) {
        int c = wid * 2 + cc;
        int grow = n0 + c * 8 + rsub;
        gload16(&pBhi[(size_t)grow * ND + k0 + 64 + slotg * 8],
                &Bs[p ^ 1][0][c * 512]);
        if (PAIR)
          gload16(&pBlo[(size_t)grow * ND + k0 + 64 + slotg * 8],
                  &Bs[p ^ 1][NBUF - 1][c * 512]);
      }
    }
    // compute on buffer p
#pragma unroll
    for (int kk = 0; kk < 64; kk += 32) {
      int sig = (kk >> 3) + (lane >> 4);
      bf16x8 ah, al, bh[2], bl[2];
      {
        int r = wm * 16 + (lane & 15);
        int off = r * 128 + ((sig ^ (r & 7)) << 4);
        ah = *(const bf16x8*)((const char*)&As[p][0][0] + off);
        if (PAIR) al = *(const bf16x8*)((const char*)&As[p][NBUF - 1][0] + off);
      }
#pragma unroll
      for (int fn = 0; fn < 2; ++fn) {
        int r = wn * 32 + fn * 16 + (lane & 15);
        int off = r * 128 + ((sig ^ (r & 7)) << 4);
        bh[fn] = *(const bf16x8*)((const char*)&Bs[p][0][0] + off);
        if (PAIR)
          bl[fn] = *(const bf16x8*)((const char*)&Bs[p][NBUF - 1][0] + off);
      }
#pragma unroll
      for (int fn = 0; fn < 2; ++fn) {
        acc[fn] = MFMA(ah, bh[fn], acc[fn]);
        if (PAIR) {
          acc[fn] = MFMA(ah, bl[fn], acc[fn]);
          acc[fn] = MFMA(al, bh[fn], acc[fn]);
        }
      }
    }
    if (pre) {
      // convert+write next A (vmcnt wait lands here, after MFMA)
      uint4 h = pk_hi(aun, avn);
      char* dst =
          (char*)&As[p ^ 1][0][0] + arow * 128 + ((jg ^ (arow & 7)) << 4);
      *(uint4*)dst = h;
      if (PAIR) *(uint4*)(dst + 4096) = pk_lo(aun, avn, h);
    }
    __syncthreads();  // next buffers ready; all reads of buf p done
  }

  // ---- transposed epilogue
  const int jr = lane >> 4, cl = lane & 15;
#pragma unroll
  for (int fn = 0; fn < 2; ++fn) {
    f32x4 v = acc[fn];
    int s = m0 + wm * 16 + jr * 4;
    int rh = n0 + wn * 32 + fn * 16 + cl;
    int orow = PAIR ? rh : (rh % NR) * NH + rh / NR;
    size_t o = ((size_t)b * NRH + orow) * NS + s;
    ushort4 h4;
    h4.x = rnbf(v[0]); h4.y = rnbf(v[1]);
    h4.z = rnbf(v[2]); h4.w = rnbf(v[3]);
    *(ushort4*)&C0[o] = h4;
    if (PAIR) {
      ushort4 l4;
      l4.x = rnbf(v[0] - bf2f(h4.x)); l4.y = rnbf(v[1] - bf2f(h4.y));
      l4.z = rnbf(v[2] - bf2f(h4.z)); l4.w = rnbf(v[3] - bf2f(h4.w));
      *(ushort4*)&C1[o] = l4;
    }
  }
}

// ---------------------------------------------------------------------------
// G2: T1 partials. P[z][m][e] = sum_{s in chunk z} s1[m][s]*K[s][e]
// hi/lo pair; in-kernel K transpose+convert; K fp32 regs prefetched across
// the MFMA phase. XCD decode co-locates all 48 blocks of one (b,split).
// ---------------------------------------------------------------------------
__global__ __launch_bounds__(256) void gemm_g2(
    const unsigned short* __restrict__ Ahi, const unsigned short* __restrict__ Alo,
    const float* __restrict__ Kf, float* __restrict__ P,
    int kchunk, int nz) {
  __shared__ unsigned short As[2][64 * 64];
  __shared__ unsigned short Bs[2][64 * 64];
  __shared__ float tbuf[64 * 68];
  const int tid = threadIdx.x;
  const int lane = tid & 63;
  const int wid = tid >> 6;
  const int wm = wid >> 1, wn = wid & 1;

  int lin = blockIdx.x;
  int bz, m_idx, n_idx;
  if (nz == 16) {
    int xcd = lin & 7, slot = lin >> 3;
    bz = xcd + 8 * (slot / 48);
    int rem = slot % 48;
    m_idx = rem / 16; n_idx = rem % 16;
  } else {
    bz = lin / 48;
    int rem = lin % 48;
    m_idx = rem / 16; n_idx = rem % 16;
  }
  const int m0 = m_idx * 64, n0 = n_idx * 64;
  const int b = bz % NB;
  const int kbeg = (bz / NB) * kchunk;
  const unsigned short* pAhi = Ahi + (size_t)b * NRH * NS;
  const unsigned short* pAlo = Alo + (size_t)b * NRH * NS;
  const float* pK = Kf + (size_t)b * NS * ND;

  const int rsub = lane >> 3;
  const int slotg = (lane & 7) ^ rsub;
  const int sr = tid >> 2;
  const int eg = (tid & 3) * 16;

  f32x4 acc[2][2];
#pragma unroll
  for (int i = 0; i < 2; ++i)
#pragma unroll
    for (int j = 0; j < 2; ++j) acc[i][j] = (f32x4){0.f, 0.f, 0.f, 0.f};

  float4 kr0, kr1, kr2, kr3;
  {
    const float* ksrc = pK + (size_t)(kbeg + sr) * ND + n0 + eg;
    kr0 = *(const float4*)(ksrc + 0);
    kr1 = *(const float4*)(ksrc + 4);
    kr2 = *(const float4*)(ksrc + 8);
    kr3 = *(const float4*)(ksrc + 12);
  }

  for (int k0 = kbeg; k0 < kbeg + kchunk; k0 += 64) {
#pragma unroll
    for (int cc = 0; cc < 2; ++cc) {
      int c = wid * 2 + cc;
      int grow = m0 + c * 8 + rsub;
      gload16(&pAhi[(size_t)grow * NS + k0 + slotg * 8], &As[0][c * 512]);
      gload16(&pAlo[(size_t)grow * NS + k0 + slotg * 8], &As[1][c * 512]);
    }
    {
      float* td = &tbuf[sr * 68 + eg];
      *(float4*)(td + 0) = kr0;
      *(float4*)(td + 4) = kr1;
      *(float4*)(td + 8) = kr2;
      *(float4*)(td + 12) = kr3;
    }
    __syncthreads();
    {
      const int e = tid & 63;
      const int sg = (tid >> 6) * 16;
      float v[16];
#pragma unroll
      for (int i = 0; i < 16; ++i) v[i] = tbuf[(sg + i) * 68 + e];
      float4 u0 = {v[0], v[1], v[2], v[3]},   w0 = {v[4], v[5], v[6], v[7]};
      float4 u1 = {v[8], v[9], v[10], v[11]}, w1 = {v[12], v[13], v[14], v[15]};
      uint4 h0 = pk_hi(u0, w0), h1 = pk_hi(u1, w1);
      int j0 = sg >> 3;
      char* dbase = (char*)&Bs[0][0] + e * 128;
      *(uint4*)(dbase + (((j0 + 0) ^ (e & 7)) << 4)) = h0;
      *(uint4*)(dbase + (((j0 + 1) ^ (e & 7)) << 4)) = h1;
      char* dlo = (char*)&Bs[1][0] + e * 128;
      *(uint4*)(dlo + (((j0 + 0) ^ (e & 7)) << 4)) = pk_lo(u0, w0, h0);
      *(uint4*)(dlo + (((j0 + 1) ^ (e & 7)) << 4)) = pk_lo(u1, w1, h1);
    }
    __syncthreads();
    if (k0 + 64 < kbeg + kchunk) {
      const float* ksrc = pK + (size_t)(k0 + 64 + sr) * ND + n0 + eg;
      kr0 = *(const float4*)(ksrc + 0);
      kr1 = *(const float4*)(ksrc + 4);
      kr2 = *(const float4*)(ksrc + 8);
      kr3 = *(const float4*)(ksrc + 12);
    }
#pragma unroll
    for (int kk = 0; kk < 64; kk += 32) {
      int sig = (kk >> 3) + (lane >> 4);
      bf16x8 ah[2], al[2], bh[2], bl[2];
#pragma unroll
      for (int fm = 0; fm < 2; ++fm) {
        int r = wm * 32 + fm * 16 + (lane & 15);
        int off = r * 128 + ((sig ^ (r & 7)) << 4);
        ah[fm] = *(const bf16x8*)((const char*)&As[0][0] + off);
        al[fm] = *(const bf16x8*)((const char*)&As[1][0] + off);
      }
#pragma unroll
      for (int fn = 0; fn < 2; ++fn) {
        int r = wn * 32 + fn * 16 + (lane & 15);
        int off = r * 128 + ((sig ^ (r & 7)) << 4);
        bh[fn] = *(const bf16x8*)((const char*)&Bs[0][0] + off);
        bl[fn] = *(const bf16x8*)((const char*)&Bs[1][0] + off);
      }
#pragma unroll
      for (int fm = 0; fm < 2; ++fm)
#pragma unroll
        for (int fn = 0; fn < 2; ++fn) {
          acc[fm][fn] = MFMA(ah[fm], bh[fn], acc[fm][fn]);
          acc[fm][fn] = MFMA(ah[fm], bl[fn], acc[fm][fn]);
          acc[fm][fn] = MFMA(al[fm], bh[fn], acc[fm][fn]);
        }
    }
    __syncthreads();
  }

  const int jr = lane >> 4, cl = lane & 15;
  float* pc = P + (size_t)bz * NRH * ND;
#pragma unroll
  for (int fm = 0; fm < 2; ++fm)
#pragma unroll
    for (int fn = 0; fn < 2; ++fn) {
      f32x4 v = acc[fm][fn];
      int gcol = n0 + wn * 32 + fn * 16 + cl;
#pragma unroll
      for (int j = 0; j < 4; ++j) {
        int m = m0 + wm * 32 + fm * 16 + jr * 4 + j;
        pc[(size_t)m * ND + gcol] = v[j];
      }
    }
}

// ---------------------------------------------------------------------------
// G4: lin[m][n] = sum_k ctx[m][k]*WL[n][k]; M=1536 N=1024 K=1024.
// BM=64, 2-phase pipelined, 384 blocks.
// ---------------------------------------------------------------------------
__global__ __launch_bounds__(256) void gemm_g4(
    const unsigned short* __restrict__ A, const float* __restrict__ Bf,
    float* __restrict__ lin) {
  __shared__ unsigned short As[2][64 * 64];
  __shared__ unsigned short Bs[2][64 * 64];
  const int tid = threadIdx.x;
  const int lane = tid & 63;
  const int wid = tid >> 6;
  const int wm = wid >> 1, wn = wid & 1;
  const int m0 = (blockIdx.x >> 4) * 64, n0 = (blockIdx.x & 15) * 64;
  const int rsub = lane >> 3;
  const int slotg = (lane & 7) ^ rsub;
  const int brow = tid >> 2;
  const int jbase = (tid & 3) * 2;

  f32x4 acc[2][2];
#pragma unroll
  for (int i = 0; i < 2; ++i)
#pragma unroll
    for (int j = 0; j < 2; ++j) acc[i][j] = (f32x4){0.f, 0.f, 0.f, 0.f};

#pragma unroll
  for (int cc = 0; cc < 2; ++cc) {
    int c = wid * 2 + cc;
    gload16(&A[(size_t)(m0 + c * 8 + rsub) * ND + slotg * 8], &As[0][c * 512]);
  }
  {
    const float* bsrc = Bf + (size_t)(n0 + brow) * ND + jbase * 8;
    float4 u0 = *(const float4*)(bsrc + 0), v0 = *(const float4*)(bsrc + 4);
    float4 u1 = *(const float4*)(bsrc + 8), v1 = *(const float4*)(bsrc + 12);
    char* dbase = (char*)&Bs[0][0] + brow * 128;
    *(uint4*)(dbase + (((jbase + 0) ^ (brow & 7)) << 4)) = pk_hi(u0, v0);
    *(uint4*)(dbase + (((jbase + 1) ^ (brow & 7)) << 4)) = pk_hi(u1, v1);
  }
  __syncthreads();

  int p = 0;
  for (int k0 = 0; k0 < ND; k0 += 64, p ^= 1) {
    const bool pre = (k0 + 64) < ND;
    float4 pu0 = {}, pv0 = {}, pu1 = {}, pv1 = {};
    if (pre) {
#pragma unroll
      for (int cc = 0; cc < 2; ++cc) {
        int c = wid * 2 + cc;
        gload16(&A[(size_t)(m0 + c * 8 + rsub) * ND + k0 + 64 + slotg * 8],
                &As[p ^ 1][c * 512]);
      }
      const float* bsrc = Bf + (size_t)(n0 + brow) * ND + k0 + 64 + jbase * 8;
      pu0 = *(const float4*)(bsrc + 0); pv0 = *(const float4*)(bsrc + 4);
      pu1 = *(const float4*)(bsrc + 8); pv1 = *(const float4*)(bsrc + 12);
    }
#pragma unroll
    for (int kk = 0; kk < 64; kk += 32) {
      int sig = (kk >> 3) + (lane >> 4);
      bf16x8 ah[2], bh[2];
#pragma unroll
      for (int fm = 0; fm < 2; ++fm) {
        int r = wm * 32 + fm * 16 + (lane & 15);
        int off = r * 128 + ((sig ^ (r & 7)) << 4);
        ah[fm] = *(const bf16x8*)((const char*)&As[p][0] + off);
      }
#pragma unroll
      for (int fn = 0; fn < 2; ++fn) {
        int r = wn * 32 + fn * 16 + (lane & 15);
        int off = r * 128 + ((sig ^ (r & 7)) << 4);
        bh[fn] = *(const bf16x8*)((const char*)&Bs[p][0] + off);
      }
#pragma unroll
      for (int fm = 0; fm < 2; ++fm)
#pragma unroll
        for (int fn = 0; fn < 2; ++fn)
          acc[fm][fn] = MFMA(ah[fm], bh[fn], acc[fm][fn]);
    }
    if (pre) {
      char* dbase = (char*)&Bs[p ^ 1][0] + brow * 128;
      *(uint4*)(dbase + (((jbase + 0) ^ (brow & 7)) << 4)) = pk_hi(pu0, pv0);
      *(uint4*)(dbase + (((jbase + 1) ^ (brow & 7)) << 4)) = pk_hi(pu1, pv1);
    }
    __syncthreads();
  }

  const int jr = lane >> 4, cl = lane & 15;
#pragma unroll
  for (int fm = 0; fm < 2; ++fm)
#pragma unroll
    for (int fn = 0; fn < 2; ++fn) {
      f32x4 v = acc[fm][fn];
      int gcol = n0 + wn * 32 + fn * 16 + cl;
#pragma unroll
      for (int j = 0; j < 4; ++j) {
        int m = m0 + wm * 32 + fm * 16 + jr * 4 + j;
        lin[(size_t)m * ND + gcol] = v[j];
      }
    }
}

// ---------------------------------------------------------------------------
// bias + LayerNorm -> out
// ---------------------------------------------------------------------------
__global__ __launch_bounds__(256) void bias_ln(const float* __restrict__ lin,
                                               const float* __restrict__ bias,
                                               const float* __restrict__ gamma,
                                               const float* __restrict__ beta,
                                               float* __restrict__ out) {
  int row = blockIdx.x;
  int t = threadIdx.x;
  float4 a = ((const float4*)(lin + (size_t)row * ND))[t];
  float4 bv = ((const float4*)bias)[t];
  a.x += bv.x; a.y += bv.y; a.z += bv.z; a.w += bv.w;

  float s = a.x + a.y + a.z + a.w;
  float ss = a.x * a.x + a.y * a.y + a.z * a.z + a.w * a.w;
#pragma unroll
  for (int off = 32; off > 0; off >>= 1) {
    s += __shfl_xor(s, off);
    ss += __shfl_xor(ss, off);
  }
  __shared__ float red[8];
  int wave = t >> 6, lane = t & 63;
  if (lane == 0) { red[wave] = s; red[4 + wave] = ss; }
  __syncthreads();
  s = red[0] + red[1] + red[2] + red[3];
  ss = red[4] + red[5] + red[6] + red[7];
  float mu = s * (1.0f / ND);
  float var = ss * (1.0f / ND) - mu * mu;
  float inv = rsqrtf(var + 1e-6f);
  float4 g = ((const float4*)gamma)[t];
  float4 be = ((const float4*)beta)[t];
  float4 o;
  o.x = (a.x - mu) * inv * g.x + be.x;
  o.y = (a.y - mu) * inv * g.y + be.y;
  o.z = (a.z - mu) * inv * g.z + be.z;
  o.w = (a.w - mu) * inv * g.w + be.w;
  ((float4*)(out + (size_t)row * ND))[t] = o;
}

// ---------------------------------------------------------------------------
// sm_k: one block per (b,h,r). Sums G2's split partials inline.
// ---------------------------------------------------------------------------
__global__ __launch_bounds__(256) void sm_k(const float* __restrict__ P,
                                            int nsplit,
                                            const float* __restrict__ WK,
                                            const float* __restrict__ WV,
                                            unsigned short* __restrict__ A2) {
  int x = blockIdx.x;
  int xcd = x & 7, within = x >> 3;
  int h = xcd + 8 * (within & 1);
  int rb = within >> 1;
  int r = rb >> 2, b = rb & 3;
  int idx = (b * NH + h) * NR + r;
  int rh = h * NR + r;

  const int t = threadIdx.x;
  const int lane = t & 63, wv = t >> 6;
  __shared__ float t1s[ND];
  __shared__ float s2s[NDH];
  __shared__ float attns[NDH];

  {
    const size_t sstride = (size_t)NB * NRH * ND;
    const float* base = P + ((size_t)b * NRH + rh) * ND;
    float4 a = ((const float4*)base)[t];
    for (int s = 1; s < nsplit; ++s) {
      float4 v = ((const float4*)(base + (size_t)s * sstride))[t];
      a.x += v.x; a.y += v.y; a.z += v.z; a.w += v.w;
    }
    ((float4*)t1s)[t] = a;
  }
  __syncthreads();

  for (int j = 0; j < 16; ++j) {
    int d = wv * 16 + j;
    const float* row = WK + (size_t)(h * NDH + d) * ND;
    float acc = 0.f;
#pragma unroll
    for (int i = 0; i < 16; ++i) acc += row[lane + i * 64] * t1s[lane + i * 64];
#pragma unroll
    for (int off = 32; off > 0; off >>= 1) acc += __shfl_xor(acc, off);
    if (lane == 0) s2s[d] = acc;
  }
  __syncthreads();

  if (t < NDH) {
    float s2 = s2s[t];
    float m = s2;
#pragma unroll
    for (int off = 32; off > 0; off >>= 1) m = fmaxf(m, __shfl_xor(m, off));
    float e = __expf(s2 - m);
    float sum = e;
#pragma unroll
    for (int off = 32; off > 0; off >>= 1) sum += __shfl_xor(sum, off);
    attns[t] = e / sum;
  }
  __syncthreads();

  {
    int e0 = t * 4;
    const float* wvp = WV + (size_t)h * NDH * ND + e0;
    float a0 = 0.f, a1 = 0.f, a2 = 0.f, a3 = 0.f;
#pragma unroll 4
    for (int dd = 0; dd < NDH; ++dd) {
      float4 wvv = *(const float4*)&wvp[(size_t)dd * ND];
      float a = attns[dd];
      a0 += a * wvv.x; a1 += a * wvv.y; a2 += a * wvv.z; a3 += a * wvv.w;
    }
    ushort4 o;
    o.x = rnbf(a0); o.y = rnbf(a1); o.z = rnbf(a2); o.w = rnbf(a3);
    *(ushort4*)&A2[(size_t)idx * ND + e0] = o;
  }
}

// ---------------------------------------------------------------------------
extern "C" void kernel_launch(void* const* d_in, const int* in_sizes, int n_in,
                              void* d_out, int out_size, void* d_ws, size_t ws_size,
                              hipStream_t stream) {
  const float* Q = (const float*)d_in[0];
  const float* K = (const float*)d_in[1];
  const float* V = (const float*)d_in[2];
  const float* U = (const float*)d_in[3];
  const float* WQ = (const float*)d_in[4];
  const float* WK = (const float*)d_in[5];
  const float* WV = (const float*)d_in[6];
  const float* WL = (const float*)d_in[7];
  const float* bl = (const float*)d_in[8];
  const float* ga = (const float*)d_in[9];
  const float* be = (const float*)d_in[10];
  float* out = (float*)d_out;
  char* w = (char*)d_ws;

  unsigned short* wqhi = (unsigned short*)w;
  unsigned short* wqlo = (unsigned short*)(w + 1572864);
  unsigned short* A2b = wqhi;  // reuse after G1t
  unsigned short* s1hi = (unsigned short*)(w + 3145728);
  unsigned short* s1lo = (unsigned short*)(w + 6291456);
  unsigned short* ctxb = (unsigned short*)(w + 9437184);
  float* lin = (float*)(w + 12582912);
  float* P = (float*)(w + 18874368);

  size_t avail = ws_size > 18874368 ? ws_size - 18874368 : 0;
  int sG2 = 1;
  while (sG2 * 2 <= 4 && 3145728ull * (size_t)(sG2 * 2) <= avail) sG2 *= 2;

  build_wqeff<<<NB * NH * NR, 256, 0, stream>>>(U, WQ, wqhi, wqlo);

  // G1t: s1^T, BM=32, 768 blocks, 2-phase, XCD-decoded.
  gemm_tn<true><<<768, 256, 0, stream>>>(Q, wqhi, wqlo, s1hi, s1lo);

  // G2: split-K partials, fused K transpose+convert, K-reg prefetch.
  gemm_g2<<<48 * NB * sG2, 256, 0, stream>>>(s1hi, s1lo, K, P, 2048 / sG2,
                                             NB * sG2);

  // s2 -> softmax -> A2 (sums G2 partials inline)
  sm_k<<<NB * NH * NR, 256, 0, stream>>>(P, sG2, WK, WV, A2b);

  // G3t: ctx^T, BM=32, 768 blocks, 2-phase, XCD-decoded.
  gemm_tn<false><<<768, 256, 0, stream>>>(V, A2b, nullptr, ctxb, nullptr);

  // G4: lin = ctx @ WL^T, BM=64, 2-phase, 384 blocks.
  gemm_g4<<<384, 256, 0, stream>>>(ctxb, WL, lin);

  // bias + LayerNorm -> out
  bias_ln<<<NB * 384, 256, 0, stream>>>(lin, bl, ga, be, out);
}